// Round 9
// baseline (232.512 us; speedup 1.0000x reference)
//
#include <hip/hip_runtime.h>
#include <hip/hip_bf16.h>

typedef __attribute__((ext_vector_type(8))) short bf16x8;
typedef __attribute__((ext_vector_type(4))) float f32x4;
typedef __attribute__((ext_vector_type(8))) unsigned short ushort8;

typedef __attribute__((address_space(1))) void gvoid_as1;
typedef __attribute__((address_space(3))) void lvoid_as3;

__device__ __forceinline__ void gload_lds16(const void* g, void* l) {
  __builtin_amdgcn_global_load_lds((const gvoid_as1*)g, (lvoid_as3*)l, 16, 0, 0);
}

__device__ __forceinline__ unsigned short f2b(float f) {
  __hip_bfloat16 h = __float2bfloat16(f);
  return __builtin_bit_cast(unsigned short, h);
}

// ---------------- f32 -> bf16 convert, x and W in one dispatch --------------
__global__ __launch_bounds__(256) void cvt_all(const float* __restrict__ x,
                                               const float* __restrict__ W,
                                               unsigned short* __restrict__ xb,
                                               unsigned short* __restrict__ wb) {
  int i = blockIdx.x * blockDim.x + threadIdx.x;
  const float* src;
  unsigned short* dst;
  int j;
  if (i < 3145728) {            // x: 8*2048*768 f32 = 3145728 float4
    src = x; dst = xb; j = i;
  } else {                      // W: 2304*768 = 442368 float4
    src = W; dst = wb; j = i - 3145728;
    if (j >= 442368) return;
  }
  float4 v = reinterpret_cast<const float4*>(src)[j];
  ushort4 o;
  o.x = f2b(v.x); o.y = f2b(v.y); o.z = f2b(v.z); o.w = f2b(v.w);
  reinterpret_cast<ushort4*>(dst)[j] = o;
}

// ------- 128x128 BK=64 GEMM, 2 waves x (128x64 wave-tile) -------------------
// LDS-port accounting: staged 15.6 + read 22.9 = 38.5 B/KFLOP (vs 45.8 at
// 4-wave 64x64) -> ~810 TF port ceiling. 4 blocks/CU (LDS 32KB, VGPR<=256).
// C[m,n] = sum_k A[m,k]*B[n,k]  (both operands K-contiguous rows)
// EPI 0: QKV — bf16 out; +bias; cols<768 *=scale (Q); cols>=1536 -> vt^T (V)
// EPI 1: scores — bf16 out = exp(s); per-row partial sums -> Lpart[row][32]
// EPI 2: PV — f32 out = acc * Linv[row]
template<int EPI>
__global__ __launch_bounds__(128, 2)
void gemm128(const unsigned short* __restrict__ A, int lda, long sA,
             const unsigned short* __restrict__ Bm, int ldb, long sB,
             void* __restrict__ Cv, int ldc, long sC,
             const float* __restrict__ bias, float scale,
             unsigned short* __restrict__ vt,
             float* __restrict__ Lpart, const float* __restrict__ Linv, int K) {
  __shared__ unsigned short lsAB[16384];  // A @0 (16KB), B @8192 (16KB)
  char* const lds = (char*)lsAB;
  const int tid = threadIdx.x;
  const int lane = tid & 63;
  const int wv = tid >> 6;            // 0..1 — column half
  const int wc = wv * 64;
  const int lr = lane & 15;
  const int lkb = (lane >> 4) * 16;   // 16B k-oct within 64B k-slice
  const int swz = (lane & 7) << 4;    // read-side XOR (row&7 == lr&7)

  // bijective XCD-aware swizzle on the xy-plane (all grids: nwg%8==0)
  const int gx = gridDim.x;
  const int nwg = gx * gridDim.y;
  const int orig = blockIdx.y * gx + blockIdx.x;
  const int xcd = orig & 7, idx = orig >> 3;
  const int q8 = nwg >> 3, r8 = nwg & 7;
  const int wg = (xcd < r8 ? xcd * (q8 + 1) : r8 * (q8 + 1) + (xcd - r8) * q8) + idx;
  const int brow = (wg / gx) * 128;
  const int bcol = (wg % gx) * 128;

  const unsigned short* Ab = A + (size_t)blockIdx.z * sA;
  const unsigned short* Bb = Bm + (size_t)blockIdx.z * sB;

  f32x4 acc[8][4];
#pragma unroll
  for (int m = 0; m < 8; m++)
#pragma unroll
    for (int n = 0; n < 4; n++) acc[m][n] = (f32x4){0.f, 0.f, 0.f, 0.f};

  for (int kk = 0; kk < K; kk += 64) {
    // stage 128x64 A and B tiles: 1024 16B segs each, 8 per thread per op.
    // seg s -> row r=s>>3, pre-swizzled global col ((s&7)^(r&7))*8; LDS linear.
#pragma unroll
    for (int j = 0; j < 8; j++) {
      const int s = tid + j * 128;
      const int r = s >> 3;
      const int c = ((s & 7) ^ (r & 7)) * 8;
      gload_lds16(Ab + (size_t)(brow + r) * lda + kk + c, lds + s * 16);
      gload_lds16(Bb + (size_t)(bcol + r) * ldb + kk + c, lds + 16384 + s * 16);
    }
    __syncthreads();  // drains vmcnt; cross-block overlap hides the stall
#pragma unroll
    for (int ks = 0; ks < 2; ks++) {
      bf16x8 af[8], bfr[4];
#pragma unroll
      for (int m = 0; m < 8; m++)
        af[m] = *(const bf16x8*)(lds + (m * 16 + lr) * 128 +
                                 ((ks * 64 + lkb) ^ swz));
#pragma unroll
      for (int n = 0; n < 4; n++)
        bfr[n] = *(const bf16x8*)(lds + 16384 + (wc + n * 16 + lr) * 128 +
                                  ((ks * 64 + lkb) ^ swz));
#pragma unroll
      for (int m = 0; m < 8; m++)
#pragma unroll
        for (int n = 0; n < 4; n++)
          acc[m][n] = __builtin_amdgcn_mfma_f32_16x16x32_bf16(af[m], bfr[n], acc[m][n], 0, 0, 0);
    }
    __syncthreads();  // protect LDS before next-iter staging
  }

  // ---- epilogue. C/D frag layout: col=lane&15, row=(lane>>4)*4+reg ----
  if (EPI == 2) {
    // f32 out, scaled by per-row 1/l
    float* C = (float*)Cv + (size_t)blockIdx.z * sC;
    const int r0e = brow + (lane >> 4) * 4;
    const int c0e = bcol + wc + lr;
    const float* Lb = Linv + (size_t)blockIdx.z * 2048;
    float li[8][4];
#pragma unroll
    for (int m = 0; m < 8; m++)
#pragma unroll
      for (int j = 0; j < 4; j++) li[m][j] = Lb[r0e + m * 16 + j];
#pragma unroll
    for (int m = 0; m < 8; m++)
#pragma unroll
      for (int n = 0; n < 4; n++)
#pragma unroll
        for (int j = 0; j < 4; j++)
          C[(size_t)(r0e + m * 16 + j) * ldc + (c0e + n * 16)] =
              acc[m][n][j] * li[m][j];
  } else {
    // bf16 path: round-trip through LDS (reuse 32KB) for ushort8 stores.
    const bool isV = (EPI == 0) && (bcol >= 1536);
    const bool isQ = (EPI == 0) && (bcol < 768);
    float bv[4];
    if (EPI == 0) {
#pragma unroll
      for (int n = 0; n < 4; n++) bv[n] = bias[bcol + wc + n * 16 + lr];
    }
    float rs[8][4];  // per-(m,j) row partial sums (EPI 1)
    if (EPI == 1) {
#pragma unroll
      for (int m = 0; m < 8; m++)
#pragma unroll
        for (int j = 0; j < 4; j++) rs[m][j] = 0.f;
    }
    // write acc -> LDS tile [128][128] bf16, slot ^= (row&15)
#pragma unroll
    for (int m = 0; m < 8; m++)
#pragma unroll
      for (int n = 0; n < 4; n++)
#pragma unroll
        for (int j = 0; j < 4; j++) {
          float v = acc[m][n][j];
          if (EPI == 0) {
            v += bv[n];
            if (isQ) v *= scale;
          }
          if (EPI == 1) {
            v = exp2f(v * 1.4426950408889634f);  // exp(s), no max needed
            rs[m][j] += v;
          }
          const int R = m * 16 + (lane >> 4) * 4 + j;  // local row
          const int Cc = wc + n * 16 + lr;             // local col
          const int row_ = isV ? Cc : R;
          const int col_ = isV ? R : Cc;
          *(unsigned short*)(lds + row_ * 256 +
                             ((col_ * 2) ^ ((row_ & 15) << 4))) = f2b(v);
        }
    if (EPI == 1) {
      // reduce rs across the 16 col-lanes (this wave's 64-col half)
#pragma unroll
      for (int m = 0; m < 8; m++)
#pragma unroll
        for (int j = 0; j < 4; j++) {
          float s = rs[m][j];
          s += __shfl_xor(s, 1);
          s += __shfl_xor(s, 2);
          s += __shfl_xor(s, 4);
          s += __shfl_xor(s, 8);
          rs[m][j] = s;
        }
      if (lr == 0) {
        float* Lp = Lpart + ((size_t)blockIdx.z * 2048 + brow +
                             (lane >> 4) * 4) * 32 + (bcol >> 7) * 2 + wv;
#pragma unroll
        for (int m = 0; m < 8; m++)
#pragma unroll
          for (int j = 0; j < 4; j++) Lp[(size_t)(m * 16 + j) * 32] = rs[m][j];
      }
    }
    __syncthreads();
    // read back rows, 16B chunks; chunk (row, sl) holds cols sl*8..+7
    if (isV) {
      const int b = brow >> 11;        // batch (BM=128 never straddles)
      const int l0 = brow & 2047;
      const int e0 = bcol - 1536;
      unsigned short* dst = vt + ((size_t)b * 768 + e0) * 2048 + l0;
#pragma unroll
      for (int i = 0; i < 16; i++) {
        const int id = tid + i * 128;
        const int row = id >> 4, sl = id & 15;
        ushort8 vv = *(const ushort8*)(lds + row * 256 +
                                       ((sl * 16) ^ ((row & 15) << 4)));
        *(ushort8*)(dst + (size_t)row * 2048 + sl * 8) = vv;
      }
    } else {
      unsigned short* C = (unsigned short*)Cv + (size_t)blockIdx.z * sC +
                          (size_t)brow * ldc + bcol;
#pragma unroll
      for (int i = 0; i < 16; i++) {
        const int id = tid + i * 128;
        const int row = id >> 4, sl = id & 15;
        ushort8 vv = *(const ushort8*)(lds + row * 256 +
                                       ((sl * 16) ^ ((row & 15) << 4)));
        *(ushort8*)(C + (size_t)row * ldc + sl * 8) = vv;
      }
    }
  }
}

// ---------------- Lpart[rows][32] -> Linv[rows] = 1/sum ---------------------
__global__ __launch_bounds__(256) void sum_l(const float* __restrict__ Lpart,
                                             float* __restrict__ Linv, int nrows) {
  int r = blockIdx.x * blockDim.x + threadIdx.x;
  if (r >= nrows) return;
  const float4* p = (const float4*)(Lpart + (size_t)r * 32);
  float s = 0.f;
#pragma unroll
  for (int i = 0; i < 8; i++) {
    float4 v = p[i];
    s += (v.x + v.y) + (v.z + v.w);
  }
  Linv[r] = 1.0f / s;
}

// ---------------- host ------------------------------------------------------
extern "C" void kernel_launch(void* const* d_in, const int* in_sizes, int n_in,
                              void* d_out, int out_size, void* d_ws, size_t ws_size,
                              hipStream_t stream) {
  const float* x = (const float*)d_in[0];
  const float* W = (const float*)d_in[1];
  const float* bias = (const float*)d_in[2];
  float* out = (float*)d_out;
  char* ws = (char*)d_ws;

  unsigned short* xb = (unsigned short*)(ws);
  unsigned short* wb = (unsigned short*)(ws + 25165824);
  unsigned short* qkv = (unsigned short*)(ws + 28704768);
  unsigned short* vt = (unsigned short*)(ws + 104202240);
  unsigned short* S = (unsigned short*)(ws + 129368064);
  // Lpart/Linv reuse the xb region (xb is dead after the QKV GEMM):
  float* Lpart = (float*)(ws);                 // 16384*32*4 = 2 MB
  float* Linv = (float*)(ws + 2097152);        // 16384*4 = 64 KB
  const float scale = 0.03608439182435161f;    // 768^-0.5

  cvt_all<<<14016, 256, 0, stream>>>(x, W, xb, wb);
  // QKV = x @ W^T + b : M=16384 N=2304 K=768; Q scaled; V written to vt^T
  gemm128<0><<<dim3(18, 128, 1), 128, 0, stream>>>(
      xb, 768, 0, wb, 768, 0, qkv, 2304, 0, bias, scale, vt,
      nullptr, nullptr, 768);

  bool batched = ws_size >= (129368064UL + 67108864UL);
  if (batched) {
    // P~ = exp(Q @ K^T) per batch (scale folded into Q): M=N=2048 K=768
    gemm128<1><<<dim3(16, 16, 8), 128, 0, stream>>>(
        qkv, 2304, 2048L * 2304, qkv + 768, 2304, 2048L * 2304,
        S, 2048, 2048L * 2048, nullptr, 1.f, nullptr, Lpart, nullptr, 768);
    sum_l<<<64, 256, 0, stream>>>(Lpart, Linv, 16384);
    // out = (P~ @ V) * (1/l) : M=2048 N=768 K=2048
    gemm128<2><<<dim3(6, 16, 8), 128, 0, stream>>>(
        S, 2048, 2048L * 2048, vt, 2048, 768L * 2048,
        out, 768, 2048L * 768, nullptr, 1.f, nullptr, nullptr, Linv, 2048);
  } else {
    for (int b = 0; b < 8; b++) {
      const unsigned short* qb = qkv + (size_t)b * 2048 * 2304;
      gemm128<1><<<dim3(16, 16, 1), 128, 0, stream>>>(
          qb, 2304, 0, qb + 768, 2304, 0, S, 2048, 0, nullptr, 1.f, nullptr,
          Lpart, nullptr, 768);
      sum_l<<<8, 256, 0, stream>>>(Lpart, Linv, 2048);
      gemm128<2><<<dim3(6, 16, 1), 128, 0, stream>>>(
          S, 2048, 0, vt + (size_t)b * 768 * 2048, 2048, 0,
          out + (size_t)b * 2048 * 768, 768, 0, nullptr, 1.f, nullptr,
          nullptr, Linv, 2048);
    }
  }
}

// Round 10
// 200.891 us; speedup vs baseline: 1.1574x; 1.1574x over previous
//
#include <hip/hip_runtime.h>
#include <hip/hip_bf16.h>

typedef __attribute__((ext_vector_type(8))) short bf16x8;
typedef __attribute__((ext_vector_type(4))) float f32x4;
typedef __attribute__((ext_vector_type(8))) unsigned short ushort8;

typedef __attribute__((address_space(1))) void gvoid_as1;
typedef __attribute__((address_space(3))) void lvoid_as3;

__device__ __forceinline__ void gload_lds16(const void* g, void* l) {
  __builtin_amdgcn_global_load_lds((const gvoid_as1*)g, (lvoid_as3*)l, 16, 0, 0);
}

__device__ __forceinline__ unsigned short f2b(float f) {
  __hip_bfloat16 h = __float2bfloat16(f);
  return __builtin_bit_cast(unsigned short, h);
}

// ---------------- f32 -> bf16 convert, x and W in one dispatch --------------
__global__ __launch_bounds__(256) void cvt_all(const float* __restrict__ x,
                                               const float* __restrict__ W,
                                               unsigned short* __restrict__ xb,
                                               unsigned short* __restrict__ wb) {
  int i = blockIdx.x * blockDim.x + threadIdx.x;
  const float* src;
  unsigned short* dst;
  int j;
  if (i < 3145728) {            // x: 8*2048*768 f32 = 3145728 float4
    src = x; dst = xb; j = i;
  } else {                      // W: 2304*768 = 442368 float4
    src = W; dst = wb; j = i - 3145728;
    if (j >= 442368) return;
  }
  float4 v = reinterpret_cast<const float4*>(src)[j];
  ushort4 o;
  o.x = f2b(v.x); o.y = f2b(v.y); o.z = f2b(v.z); o.w = f2b(v.w);
  reinterpret_cast<ushort4*>(dst)[j] = o;
}

// ---------------- 128x128 BK=64 MFMA GEMM (round-4 structure) ---------------
// C[m,n] = sum_k A[m,k]*B[n,k]  (both operands K-contiguous rows)
// EPI 0: QKV — bf16 out; +bias; cols<768 *=scale (Q); cols>=1536 -> vt^T (V)
// EPI 1: scores — bf16 out = exp(s); per-row partial sums -> Lpart[row][32]
// EPI 2: PV — f32 out = acc * Linv[row], float4 stores via LDS
// LDS 32KB; T2 both-sides XOR swizzle; 3D-bijective XCD swizzle (one batch
// z-slice per XCD for QK^T/PV -> K/V panels stay L2-resident).
template<int EPI>
__global__ __launch_bounds__(256, 4)
void gemm128(const unsigned short* __restrict__ A, int lda, long sA,
             const unsigned short* __restrict__ Bm, int ldb, long sB,
             void* __restrict__ Cv, int ldc, long sC,
             const float* __restrict__ bias, float scale,
             unsigned short* __restrict__ vt,
             float* __restrict__ Lpart, const float* __restrict__ Linv, int K) {
  __shared__ unsigned short lsAB[16384];  // A @0 (16KB), B @8192 (16KB)
  char* const lds = (char*)lsAB;
  const int tid = threadIdx.x;
  const int lane = tid & 63;
  const int wv = tid >> 6;
  const int wr = (wv >> 1) * 64;
  const int wc = (wv & 1) * 64;
  const int lr = lane & 15;
  const int lkb = (lane >> 4) * 16;   // 16B k-oct within 64B k-slice
  const int swz = (lane & 7) << 4;    // read-side XOR (row&7 == lr&7)

  // 3D bijective XCD-aware swizzle over the FULL grid (z included):
  // each XCD gets a contiguous chunk of (z,y,x)-linear block ids.
  const int gx = gridDim.x;
  const int gxy = gx * gridDim.y;
  const int nwg = gxy * gridDim.z;
  const int orig = (blockIdx.z * gridDim.y + blockIdx.y) * gx + blockIdx.x;
  const int xcd = orig & 7, idx = orig >> 3;
  const int q8 = nwg >> 3, r8 = nwg & 7;
  const int wg = (xcd < r8 ? xcd * (q8 + 1) : r8 * (q8 + 1) + (xcd - r8) * q8) + idx;
  const int bz = wg / gxy;
  const int rem = wg - bz * gxy;
  const int brow = (rem / gx) * 128;
  const int bcol = (rem % gx) * 128;

  const unsigned short* Ab = A + (size_t)bz * sA;
  const unsigned short* Bb = Bm + (size_t)bz * sB;

  f32x4 acc[4][4];
#pragma unroll
  for (int m = 0; m < 4; m++)
#pragma unroll
    for (int n = 0; n < 4; n++) acc[m][n] = (f32x4){0.f, 0.f, 0.f, 0.f};

  for (int kk = 0; kk < K; kk += 64) {
    // stage 128x64 A and B tiles: 1024 16B segs each, 4 per thread per op.
    // seg s -> row r=s>>3, pre-swizzled global col ((s&7)^(r&7))*8; LDS linear.
#pragma unroll
    for (int j = 0; j < 4; j++) {
      const int s = tid + j * 256;
      const int r = s >> 3;
      const int c = ((s & 7) ^ (r & 7)) * 8;
      gload_lds16(Ab + (size_t)(brow + r) * lda + kk + c, lds + s * 16);
      gload_lds16(Bb + (size_t)(bcol + r) * ldb + kk + c, lds + 16384 + s * 16);
    }
    __syncthreads();  // drains vmcnt; cross-block overlap hides the stall
    bf16x8 af[4][2], bfr[4][2];
#pragma unroll
    for (int m = 0; m < 4; m++)
#pragma unroll
      for (int ks = 0; ks < 2; ks++)
        af[m][ks] = *(const bf16x8*)(lds + (wr + m * 16 + lr) * 128 +
                                     ((ks * 64 + lkb) ^ swz));
#pragma unroll
    for (int n = 0; n < 4; n++)
#pragma unroll
      for (int ks = 0; ks < 2; ks++)
        bfr[n][ks] = *(const bf16x8*)(lds + 16384 + (wc + n * 16 + lr) * 128 +
                                      ((ks * 64 + lkb) ^ swz));
#pragma unroll
    for (int m = 0; m < 4; m++)
#pragma unroll
      for (int n = 0; n < 4; n++) {
        acc[m][n] = __builtin_amdgcn_mfma_f32_16x16x32_bf16(af[m][0], bfr[n][0], acc[m][n], 0, 0, 0);
        acc[m][n] = __builtin_amdgcn_mfma_f32_16x16x32_bf16(af[m][1], bfr[n][1], acc[m][n], 0, 0, 0);
      }
    __syncthreads();  // protect LDS before next-iter staging
  }

  // ---- epilogue. C/D frag layout: col=lane&15, row=(lane>>4)*4+reg ----
  if (EPI == 2) {
    // f32 out * Linv[row]; float4 stores via LDS (two 64-row halves, 32KB).
    float* C = (float*)Cv + (size_t)bz * sC;
    const int r0e = brow + wr + (lane >> 4) * 4;
    const float* Lb = Linv + (size_t)bz * 2048;
    float li[4][4];
#pragma unroll
    for (int m = 0; m < 4; m++)
#pragma unroll
      for (int j = 0; j < 4; j++) li[m][j] = Lb[r0e + m * 16 + j];
    const int myh = wr >> 6;  // waves 0,1 -> half 0; waves 2,3 -> half 1
#pragma unroll
    for (int h = 0; h < 2; ++h) {
      if (myh == h) {
#pragma unroll
        for (int m = 0; m < 4; m++)
#pragma unroll
          for (int n = 0; n < 4; n++)
#pragma unroll
            for (int j = 0; j < 4; j++) {
              const int R = (wr & 63) + m * 16 + (lane >> 4) * 4 + j;  // 0..63
              const int Cc = wc + n * 16 + lr;                         // 0..127
              *(float*)(lds + R * 512 + ((Cc * 4) ^ ((R & 7) << 4))) =
                  acc[m][n][j] * li[m][j];
            }
      }
      __syncthreads();
      // read back float4 chunks; chunk (row, sl) holds cols sl*4..+3
      float* Ch = C + (size_t)(brow + h * 64) * ldc + bcol;
#pragma unroll
      for (int i = 0; i < 8; i++) {
        const int id = tid + i * 256;
        const int row = id >> 5, sl = id & 31;
        float4 vv = *(const float4*)(lds + row * 512 +
                                     ((sl * 16) ^ ((row & 7) << 4)));
        *(float4*)(Ch + (size_t)row * ldc + sl * 4) = vv;
      }
      __syncthreads();
    }
  } else {
    // bf16 path: round-trip through LDS (reuse 32KB) for ushort8 stores.
    const bool isV = (EPI == 0) && (bcol >= 1536);
    const bool isQ = (EPI == 0) && (bcol < 768);
    float bv[4];
    if (EPI == 0) {
#pragma unroll
      for (int n = 0; n < 4; n++) bv[n] = bias[bcol + wc + n * 16 + lr];
    }
    float rs[4][4];  // per-(m,j) row partial sums (EPI 1)
    if (EPI == 1) {
#pragma unroll
      for (int m = 0; m < 4; m++)
#pragma unroll
        for (int j = 0; j < 4; j++) rs[m][j] = 0.f;
    }
    // write acc -> LDS tile [128][128] bf16, slot ^= (row&15)
#pragma unroll
    for (int m = 0; m < 4; m++)
#pragma unroll
      for (int n = 0; n < 4; n++)
#pragma unroll
        for (int j = 0; j < 4; j++) {
          float v = acc[m][n][j];
          if (EPI == 0) {
            v += bv[n];
            if (isQ) v *= scale;
          }
          if (EPI == 1) {
            v = exp2f(v * 1.4426950408889634f);  // exp(s), no max needed
            rs[m][j] += v;
          }
          const int R = wr + (lane >> 4) * 4 + m * 16 + j;  // local row
          const int Cc = wc + n * 16 + lr;                  // local col
          const int row_ = isV ? Cc : R;
          const int col_ = isV ? R : Cc;
          *(unsigned short*)(lds + row_ * 256 +
                             ((col_ * 2) ^ ((row_ & 15) << 4))) = f2b(v);
        }
    if (EPI == 1) {
      // reduce rs across the 16 col-lanes (this wave's 64-col half)
#pragma unroll
      for (int m = 0; m < 4; m++)
#pragma unroll
        for (int j = 0; j < 4; j++) {
          float s = rs[m][j];
          s += __shfl_xor(s, 1);
          s += __shfl_xor(s, 2);
          s += __shfl_xor(s, 4);
          s += __shfl_xor(s, 8);
          rs[m][j] = s;
        }
      if (lr == 0) {
        float* Lp = Lpart + ((size_t)bz * 2048 + brow + wr +
                             (lane >> 4) * 4) * 32 + (bcol >> 7) * 2 + (wv & 1);
#pragma unroll
        for (int m = 0; m < 4; m++)
#pragma unroll
          for (int j = 0; j < 4; j++) Lp[(size_t)(m * 16 + j) * 32] = rs[m][j];
      }
    }
    __syncthreads();
    // read back rows, 16B chunks; chunk (row, sl) holds cols sl*8..+7
    if (isV) {
      const int b = brow >> 11;        // batch (BM=128 never straddles)
      const int l0 = brow & 2047;
      const int e0 = bcol - 1536;
      unsigned short* dst = vt + ((size_t)b * 768 + e0) * 2048 + l0;
#pragma unroll
      for (int i = 0; i < 8; i++) {
        const int id = tid + i * 256;
        const int row = id >> 4, sl = id & 15;
        ushort8 vv = *(const ushort8*)(lds + row * 256 +
                                       ((sl * 16) ^ ((row & 15) << 4)));
        *(ushort8*)(dst + (size_t)row * 2048 + sl * 8) = vv;
      }
    } else {
      unsigned short* C = (unsigned short*)Cv + (size_t)bz * sC +
                          (size_t)brow * ldc + bcol;
#pragma unroll
      for (int i = 0; i < 8; i++) {
        const int id = tid + i * 256;
        const int row = id >> 4, sl = id & 15;
        ushort8 vv = *(const ushort8*)(lds + row * 256 +
                                       ((sl * 16) ^ ((row & 15) << 4)));
        *(ushort8*)(C + (size_t)row * ldc + sl * 8) = vv;
      }
    }
  }
}

// ---------------- Lpart[rows][32] -> Linv[rows] = 1/sum ---------------------
__global__ __launch_bounds__(256) void sum_l(const float* __restrict__ Lpart,
                                             float* __restrict__ Linv, int nrows) {
  int r = blockIdx.x * blockDim.x + threadIdx.x;
  if (r >= nrows) return;
  const float4* p = (const float4*)(Lpart + (size_t)r * 32);
  float s = 0.f;
#pragma unroll
  for (int i = 0; i < 8; i++) {
    float4 v = p[i];
    s += (v.x + v.y) + (v.z + v.w);
  }
  Linv[r] = 1.0f / s;
}

// ---------------- host ------------------------------------------------------
extern "C" void kernel_launch(void* const* d_in, const int* in_sizes, int n_in,
                              void* d_out, int out_size, void* d_ws, size_t ws_size,
                              hipStream_t stream) {
  const float* x = (const float*)d_in[0];
  const float* W = (const float*)d_in[1];
  const float* bias = (const float*)d_in[2];
  float* out = (float*)d_out;
  char* ws = (char*)d_ws;

  unsigned short* xb = (unsigned short*)(ws);
  unsigned short* wb = (unsigned short*)(ws + 25165824);
  unsigned short* qkv = (unsigned short*)(ws + 28704768);
  unsigned short* vt = (unsigned short*)(ws + 104202240);
  unsigned short* S = (unsigned short*)(ws + 129368064);
  // Lpart/Linv reuse the xb region (xb is dead after the QKV GEMM):
  float* Lpart = (float*)(ws);                 // 16384*32*4 = 2 MB
  float* Linv = (float*)(ws + 2097152);        // 16384*4 = 64 KB
  const float scale = 0.03608439182435161f;    // 768^-0.5

  cvt_all<<<14016, 256, 0, stream>>>(x, W, xb, wb);
  // QKV = x @ W^T + b : M=16384 N=2304 K=768; Q scaled; V written to vt^T
  gemm128<0><<<dim3(18, 128, 1), 256, 0, stream>>>(
      xb, 768, 0, wb, 768, 0, qkv, 2304, 0, bias, scale, vt,
      nullptr, nullptr, 768);

  bool batched = ws_size >= (129368064UL + 67108864UL);
  if (batched) {
    // P~ = exp(Q @ K^T) per batch (scale folded into Q): M=N=2048 K=768
    gemm128<1><<<dim3(16, 16, 8), 256, 0, stream>>>(
        qkv, 2304, 2048L * 2304, qkv + 768, 2304, 2048L * 2304,
        S, 2048, 2048L * 2048, nullptr, 1.f, nullptr, Lpart, nullptr, 768);
    sum_l<<<64, 256, 0, stream>>>(Lpart, Linv, 16384);
    // out = (P~ @ V) * (1/l) : M=2048 N=768 K=2048
    gemm128<2><<<dim3(6, 16, 8), 256, 0, stream>>>(
        S, 2048, 2048L * 2048, vt, 2048, 768L * 2048,
        out, 768, 2048L * 768, nullptr, 1.f, nullptr, nullptr, Linv, 2048);
  } else {
    for (int b = 0; b < 8; b++) {
      const unsigned short* qb = qkv + (size_t)b * 2048 * 2304;
      gemm128<1><<<dim3(16, 16, 1), 256, 0, stream>>>(
          qb, 2304, 0, qb + 768, 2304, 0, S, 2048, 0, nullptr, 1.f, nullptr,
          Lpart, nullptr, 768);
      sum_l<<<8, 256, 0, stream>>>(Lpart, Linv, 2048);
      gemm128<2><<<dim3(6, 16, 1), 256, 0, stream>>>(
          S, 2048, 0, vt + (size_t)b * 768 * 2048, 2048, 0,
          out + (size_t)b * 2048 * 768, 768, 0, nullptr, 1.f, nullptr,
          nullptr, Linv, 2048);
    }
  }
}